// Round 1
// 990.578 us; speedup vs baseline: 1.0893x; 1.0893x over previous
//
#include <hip/hip_runtime.h>

#define NN 50000
#define NE 600000
#define HD 128

typedef __attribute__((ext_vector_type(8))) short short8;
typedef __attribute__((ext_vector_type(4))) float floatx4;

__device__ __forceinline__ unsigned short f2bf(float f) {
  unsigned int u = __builtin_bit_cast(unsigned int, f);
  u += 0x7FFFu + ((u >> 16) & 1u);
  return (unsigned short)(u >> 16);
}

// Convert 8 consecutive f32 -> bf16 fragment (two float4 loads).
__device__ __forceinline__ short8 cvt8(const float* __restrict__ p) {
  floatx4 v0 = *(const floatx4*)p;
  floatx4 v1 = *(const floatx4*)(p + 4);
  short8 r;
  r[0] = (short)f2bf(v0[0]); r[1] = (short)f2bf(v0[1]);
  r[2] = (short)f2bf(v0[2]); r[3] = (short)f2bf(v0[3]);
  r[4] = (short)f2bf(v1[0]); r[5] = (short)f2bf(v1[1]);
  r[6] = (short)f2bf(v1[2]); r[7] = (short)f2bf(v1[3]);
  return r;
}

// Pack W[K][128] f32 row-major -> bf16 in MFMA B-fragment order:
// wp[((k0*8+n0)*64 + lane)*8 + j] = W[k0*32 + (lane>>4)*8 + j][n0*16 + (lane&15)]
__global__ void pack_w(const float* __restrict__ w, unsigned short* __restrict__ wp,
                       int total) {
  int p = blockIdx.x * blockDim.x + threadIdx.x;
  if (p >= total) return;
  int j = p & 7, lane = (p >> 3) & 63, t = p >> 9;
  int n0 = t & 7, k0 = t >> 3;
  int k = k0 * 32 + (lane >> 4) * 8 + j;
  int n = n0 * 16 + (lane & 15);
  wp[p] = f2bf(w[k * HD + n]);
}

// One-time f32 -> bf16 conversion of x (8 elems/thread).
__global__ void cvt_bf16(const float* __restrict__ in,
                         unsigned short* __restrict__ out, int total8) {
  int p = blockIdx.x * blockDim.x + threadIdx.x;
  if (p >= total8) return;
  short8 r = cvt8(in + (size_t)p * 8);
  *(short8*)(out + (size_t)p * 8) = r;
}

// LDS-sourced GEMM for a wave's 16 rows x 128 cols (layers 1/2).
template <int KSTEPS>
__device__ __forceinline__ void gemm_tile(const unsigned short* a_base, int a_stride,
                                          const unsigned short* __restrict__ wp,
                                          int lane, floatx4* acc) {
  int quad = lane >> 4, l16 = lane & 15;
  for (int k0 = 0; k0 < KSTEPS; ++k0) {
    short8 a = *(const short8*)(a_base + l16 * a_stride + k0 * 32 + quad * 8);
    const unsigned short* w = wp + k0 * 4096 + lane * 8;
#pragma unroll
    for (int n0 = 0; n0 < 8; ++n0) {
      short8 b = *(const short8*)(w + n0 * 512);
      acc[n0] = __builtin_amdgcn_mfma_f32_16x16x32_bf16(a, b, acc[n0], 0, 0, 0);
    }
  }
}

__device__ __forceinline__ void store_relu_bf16(const floatx4* acc,
                                                const float* __restrict__ bias,
                                                unsigned short* out_base, int stride,
                                                int lane) {
  int quad = lane >> 4, l16 = lane & 15;
#pragma unroll
  for (int n0 = 0; n0 < 8; ++n0) {
    float bv = bias[n0 * 16 + l16];
#pragma unroll
    for (int r = 0; r < 4; ++r) {
      float v = acc[n0][r] + bv;
      v = v > 0.f ? v : 0.f;
      out_base[(quad * 4 + r) * stride + n0 * 16 + l16] = f2bf(v);
    }
  }
}

#define SH 136  // 128 + 8 pad

// XBF=1: x pre-converted to bf16 (xb); XBF=0: load x f32 and convert in-reg.
template <int XBF>
__global__ __launch_bounds__(256, 4) void edge_kernel(
    const float* __restrict__ x, const unsigned short* __restrict__ xb,
    const float* __restrict__ e, const int* __restrict__ idx,
    const unsigned short* __restrict__ w0p, const float* __restrict__ b0,
    const unsigned short* __restrict__ w1p, const float* __restrict__ b1,
    const unsigned short* __restrict__ w2p, const float* __restrict__ b2,
    const float* __restrict__ g, const float* __restrict__ bg,
    float* __restrict__ e_out, float* __restrict__ agg) {
  __shared__ __align__(16) unsigned short lh[64 * SH];  // 17408 B, per-wave regions

  int wave = threadIdx.x >> 6, lane = threadIdx.x & 63;
  int quad = lane >> 4, l16 = lane & 15;
  int ebase = blockIdx.x * 64 + wave * 16;  // this wave's first edge
  int arow = ebase + l16;                   // this lane's A row (by l16)
  int s = idx[arow], d = idx[NE + arow];

  floatx4 acc[8];
  floatx4 z = {0.f, 0.f, 0.f, 0.f};
#pragma unroll
  for (int t = 0; t < 8; ++t) acc[t] = z;

  // layer0: [16,384] @ [384,128]. A fragments straight from global:
  // K 0..127 = x[dst], 128..255 = x[src], 256..383 = e[ei].
  const float* ee = e + (size_t)arow * HD + quad * 8;
  if constexpr (XBF) {
    const unsigned short* xd = xb + (size_t)d * HD + quad * 8;
    const unsigned short* xs = xb + (size_t)s * HD + quad * 8;
#pragma unroll
    for (int k0 = 0; k0 < 12; ++k0) {
      short8 a;
      if (k0 < 4)
        a = *(const short8*)(xd + k0 * 32);
      else if (k0 < 8)
        a = *(const short8*)(xs + (k0 - 4) * 32);
      else
        a = cvt8(ee + (k0 - 8) * 32);
      const unsigned short* w = w0p + k0 * 4096 + lane * 8;
#pragma unroll
      for (int n0 = 0; n0 < 8; ++n0) {
        short8 b = *(const short8*)(w + n0 * 512);
        acc[n0] = __builtin_amdgcn_mfma_f32_16x16x32_bf16(a, b, acc[n0], 0, 0, 0);
      }
    }
  } else {
    const float* xd = x + (size_t)d * HD + quad * 8;
    const float* xs = x + (size_t)s * HD + quad * 8;
#pragma unroll
    for (int k0 = 0; k0 < 12; ++k0) {
      short8 a;
      if (k0 < 4)
        a = cvt8(xd + k0 * 32);
      else if (k0 < 8)
        a = cvt8(xs + (k0 - 4) * 32);
      else
        a = cvt8(ee + (k0 - 8) * 32);
      const unsigned short* w = w0p + k0 * 4096 + lane * 8;
#pragma unroll
      for (int n0 = 0; n0 < 8; ++n0) {
        short8 b = *(const short8*)(w + n0 * 512);
        acc[n0] = __builtin_amdgcn_mfma_f32_16x16x32_bf16(a, b, acc[n0], 0, 0, 0);
      }
    }
  }
  unsigned short* lhw = lh + wave * 16 * SH;
  store_relu_bf16(acc, b0, lhw, SH, lane);

  // layer1: [16,128] @ [128,128] + relu, h2 written back in place (per-wave
  // region; DS ops from one wave complete in order -> no hazard, no barriers).
#pragma unroll
  for (int t = 0; t < 8; ++t) acc[t] = z;
  gemm_tile<4>(lhw, SH, w1p, lane, acc);
  store_relu_bf16(acc, b1, lhw, SH, lane);

  // layer2: [16,128] @ [128,128] (no relu), keep in regs
#pragma unroll
  for (int t = 0; t < 8; ++t) acc[t] = z;
  gemm_tile<4>(lhw, SH, w2p, lane, acc);

  // bias + LayerNorm (rows r_local = quad*4+r, cols n0*16+l16)
  float h3[8][4];
#pragma unroll
  for (int n0 = 0; n0 < 8; ++n0) {
    float bv = b2[n0 * 16 + l16];
#pragma unroll
    for (int r = 0; r < 4; ++r) h3[n0][r] = acc[n0][r] + bv;
  }
  float s1[4] = {0.f, 0.f, 0.f, 0.f}, s2[4] = {0.f, 0.f, 0.f, 0.f};
#pragma unroll
  for (int n0 = 0; n0 < 8; ++n0)
#pragma unroll
    for (int r = 0; r < 4; ++r) {
      s1[r] += h3[n0][r];
      s2[r] += h3[n0][r] * h3[n0][r];
    }
#pragma unroll
  for (int m = 1; m < 16; m <<= 1) {
#pragma unroll
    for (int r = 0; r < 4; ++r) {
      s1[r] += __shfl_xor(s1[r], m, 64);
      s2[r] += __shfl_xor(s2[r], m, 64);
    }
  }
  float mu[4], rs[4];
#pragma unroll
  for (int r = 0; r < 4; ++r) {
    mu[r] = s1[r] * (1.f / 128.f);
    float var = s2[r] * (1.f / 128.f) - mu[r] * mu[r];
    rs[r] = rsqrtf(var + 1e-5f);
  }
  // write e_new + scatter-add into agg[dst]
  int drow[4];
#pragma unroll
  for (int r = 0; r < 4; ++r) drow[r] = idx[NE + ebase + quad * 4 + r];
#pragma unroll
  for (int n0 = 0; n0 < 8; ++n0) {
    int col = n0 * 16 + l16;
    float gv = g[col], bv = bg[col];
#pragma unroll
    for (int r = 0; r < 4; ++r) {
      int ei = ebase + quad * 4 + r;
      float v = (h3[n0][r] - mu[r]) * rs[r] * gv + bv;
      e_out[(size_t)ei * HD + col] = v;
      atomicAdd(&agg[(size_t)drow[r] * HD + col], v);
    }
  }
}

template <int XBF>
__global__ __launch_bounds__(256, 4) void node_kernel(
    const float* __restrict__ x, const unsigned short* __restrict__ xb,
    const float* __restrict__ agg, const unsigned short* __restrict__ w0p,
    const float* __restrict__ b0, const unsigned short* __restrict__ w1p,
    const float* __restrict__ b1, const unsigned short* __restrict__ w2p,
    const float* __restrict__ b2, const float* __restrict__ g,
    const float* __restrict__ bg, float* __restrict__ x_out) {
  __shared__ __align__(16) unsigned short lh[64 * SH];

  int wave = threadIdx.x >> 6, lane = threadIdx.x & 63;
  int quad = lane >> 4, l16 = lane & 15;
  int nbase = blockIdx.x * 64 + wave * 16;
  int arow = nbase + l16;
  int nc = arow < NN ? arow : NN - 1;

  floatx4 acc[8];
  floatx4 z = {0.f, 0.f, 0.f, 0.f};
#pragma unroll
  for (int t = 0; t < 8; ++t) acc[t] = z;

  // layer0: [16,256] @ [256,128]. K 0..127 = x[n], 128..255 = agg[n].
  const float* ar = agg + (size_t)nc * HD + quad * 8;
  if constexpr (XBF) {
    const unsigned short* xr = xb + (size_t)nc * HD + quad * 8;
#pragma unroll
    for (int k0 = 0; k0 < 8; ++k0) {
      short8 a;
      if (k0 < 4)
        a = *(const short8*)(xr + k0 * 32);
      else
        a = cvt8(ar + (k0 - 4) * 32);
      const unsigned short* w = w0p + k0 * 4096 + lane * 8;
#pragma unroll
      for (int n0 = 0; n0 < 8; ++n0) {
        short8 b = *(const short8*)(w + n0 * 512);
        acc[n0] = __builtin_amdgcn_mfma_f32_16x16x32_bf16(a, b, acc[n0], 0, 0, 0);
      }
    }
  } else {
    const float* xr = x + (size_t)nc * HD + quad * 8;
#pragma unroll
    for (int k0 = 0; k0 < 8; ++k0) {
      short8 a;
      if (k0 < 4)
        a = cvt8(xr + k0 * 32);
      else
        a = cvt8(ar + (k0 - 4) * 32);
      const unsigned short* w = w0p + k0 * 4096 + lane * 8;
#pragma unroll
      for (int n0 = 0; n0 < 8; ++n0) {
        short8 b = *(const short8*)(w + n0 * 512);
        acc[n0] = __builtin_amdgcn_mfma_f32_16x16x32_bf16(a, b, acc[n0], 0, 0, 0);
      }
    }
  }
  unsigned short* lhw = lh + wave * 16 * SH;
  store_relu_bf16(acc, b0, lhw, SH, lane);

#pragma unroll
  for (int t = 0; t < 8; ++t) acc[t] = z;
  gemm_tile<4>(lhw, SH, w1p, lane, acc);
  store_relu_bf16(acc, b1, lhw, SH, lane);

#pragma unroll
  for (int t = 0; t < 8; ++t) acc[t] = z;
  gemm_tile<4>(lhw, SH, w2p, lane, acc);

  float h3[8][4];
#pragma unroll
  for (int n0 = 0; n0 < 8; ++n0) {
    float bv = b2[n0 * 16 + l16];
#pragma unroll
    for (int r = 0; r < 4; ++r) h3[n0][r] = acc[n0][r] + bv;
  }
  float s1[4] = {0.f, 0.f, 0.f, 0.f}, s2[4] = {0.f, 0.f, 0.f, 0.f};
#pragma unroll
  for (int n0 = 0; n0 < 8; ++n0)
#pragma unroll
    for (int r = 0; r < 4; ++r) {
      s1[r] += h3[n0][r];
      s2[r] += h3[n0][r] * h3[n0][r];
    }
#pragma unroll
  for (int m = 1; m < 16; m <<= 1) {
#pragma unroll
    for (int r = 0; r < 4; ++r) {
      s1[r] += __shfl_xor(s1[r], m, 64);
      s2[r] += __shfl_xor(s2[r], m, 64);
    }
  }
  float mu[4], rs[4];
#pragma unroll
  for (int r = 0; r < 4; ++r) {
    mu[r] = s1[r] * (1.f / 128.f);
    float var = s2[r] * (1.f / 128.f) - mu[r] * mu[r];
    rs[r] = rsqrtf(var + 1e-5f);
  }
#pragma unroll
  for (int n0 = 0; n0 < 8; ++n0) {
    int col = n0 * 16 + l16;
    float gv = g[col], bv = bg[col];
#pragma unroll
    for (int r = 0; r < 4; ++r) {
      int ni = nbase + quad * 4 + r;
      if (ni < NN) {
        float v = (h3[n0][r] - mu[r]) * rs[r] * gv + bv;
        x_out[(size_t)ni * HD + col] = x[(size_t)ni * HD + col] + v;
      }
    }
  }
}

extern "C" void kernel_launch(void* const* d_in, const int* in_sizes, int n_in,
                              void* d_out, int out_size, void* d_ws, size_t ws_size,
                              hipStream_t stream) {
  const float* x = (const float*)d_in[0];
  const float* e = (const float*)d_in[1];
  const int* idx = (const int*)d_in[2];
  const float* we0 = (const float*)d_in[3];
  const float* be0 = (const float*)d_in[4];
  const float* we1 = (const float*)d_in[5];
  const float* be1 = (const float*)d_in[6];
  const float* we2 = (const float*)d_in[7];
  const float* be2 = (const float*)d_in[8];
  const float* ge = (const float*)d_in[9];
  const float* bge = (const float*)d_in[10];
  const float* wn0 = (const float*)d_in[11];
  const float* bn0 = (const float*)d_in[12];
  const float* wn1 = (const float*)d_in[13];
  const float* bn1 = (const float*)d_in[14];
  const float* wn2 = (const float*)d_in[15];
  const float* bn2 = (const float*)d_in[16];
  const float* gn = (const float*)d_in[17];
  const float* bgn = (const float*)d_in[18];

  float* xout = (float*)d_out;                    // [N,128]; doubles as agg buffer
  float* eout = (float*)d_out + (size_t)NN * HD;  // [E,128]

  unsigned short* ws = (unsigned short*)d_ws;
  unsigned short* w0p = ws;                // 384*128
  unsigned short* w1p = w0p + 384 * HD;    // 128*128
  unsigned short* w2p = w1p + HD * HD;     // 128*128
  unsigned short* wn0p = w2p + HD * HD;    // 256*128
  unsigned short* wn1p = wn0p + 256 * HD;  // 128*128
  unsigned short* wn2p = wn1p + HD * HD;   // 128*128
  unsigned short* xb = wn2p + HD * HD;     // NN*128 bf16 copy of x (12.8 MB)

  size_t w_shorts = (size_t)(384 + 128 + 128 + 256 + 128 + 128) * HD;
  bool use_xb = ws_size >= (w_shorts + (size_t)NN * HD) * sizeof(unsigned short);

  hipMemsetAsync(xout, 0, (size_t)NN * HD * sizeof(float), stream);

  pack_w<<<(384 * HD + 255) / 256, 256, 0, stream>>>(we0, w0p, 384 * HD);
  pack_w<<<(HD * HD + 255) / 256, 256, 0, stream>>>(we1, w1p, HD * HD);
  pack_w<<<(HD * HD + 255) / 256, 256, 0, stream>>>(we2, w2p, HD * HD);
  pack_w<<<(256 * HD + 255) / 256, 256, 0, stream>>>(wn0, wn0p, 256 * HD);
  pack_w<<<(HD * HD + 255) / 256, 256, 0, stream>>>(wn1, wn1p, HD * HD);
  pack_w<<<(HD * HD + 255) / 256, 256, 0, stream>>>(wn2, wn2p, HD * HD);

  if (use_xb) {
    cvt_bf16<<<(NN * HD / 8 + 255) / 256, 256, 0, stream>>>(x, xb, NN * HD / 8);
    edge_kernel<1><<<NE / 64, 256, 0, stream>>>(x, xb, e, idx, w0p, be0, w1p, be1,
                                                w2p, be2, ge, bge, eout, xout);
    node_kernel<1><<<(NN + 63) / 64, 256, 0, stream>>>(
        x, xb, xout, wn0p, bn0, wn1p, bn1, wn2p, bn2, gn, bgn, xout);
  } else {
    edge_kernel<0><<<NE / 64, 256, 0, stream>>>(x, xb, e, idx, w0p, be0, w1p, be1,
                                                w2p, be2, ge, bge, eout, xout);
    node_kernel<0><<<(NN + 63) / 64, 256, 0, stream>>>(
        x, xb, xout, wn0p, bn0, wn1p, bn1, wn2p, bn2, gn, bgn, xout);
  }
}